// Round 3
// baseline (225.323 us; speedup 1.0000x reference)
//
#include <hip/hip_runtime.h>

#define B_ 32
#define N_ 4096
#define C_ 16
#define D_ 256
#define NSPLIT 32
#define ROWS (N_ / NSPLIT)   // 128 rows per block
#define RPW  (ROWS / 4)      // 32 rows per wave
#define NGRP (RPW / 4)       // 8 groups of 4 rows per wave

// ---------------- Stage 1: deep-ring partial sums -> ws (no atomics) -------
// Measured-best geometry (R0 = 200.7us): NSPLIT=32, 1024 blocks =
// 4 blocks/CU (16 waves/CU). One wave = one full row of D (64 lanes x
// float4). Ring of 8 rows in flight: consume row R, immediately reissue
// its slot for row R+8 -> 8 KB outstanding/wave, 128 KB/CU. Masks: one
// 64-lane r-load covers a 4-row group; ballot -> wave-uniform 16-bit
// masks in SGPRs; accumulation acc[c] += v * m with m in {0,1} (scalar
// select feeding FMA, no divergence). Special (all-below) row: p = 2^-16
// -> wave-uniform s_cbranch skip instead of x0 FMAs.
__global__ __launch_bounds__(256, 4)
void tf_stage1(const float* __restrict__ r,
               const float* __restrict__ v,
               float* __restrict__ ws) {
    const int b     = blockIdx.x >> 5;           // / NSPLIT
    const int chunk = blockIdx.x & (NSPLIT - 1);
    const int tid   = threadIdx.x;
    const int wave  = tid >> 6;
    const int lane  = tid & 63;
    const int d4    = lane << 2;

    const float* __restrict__ rb = r + (size_t)b * N_ * C_;
    const float* __restrict__ vp = v + (size_t)b * N_ * D_;

    float4 acc[17];                              // [16] = special (all-below)
#pragma unroll
    for (int c = 0; c < 17; ++c) acc[c] = make_float4(0.f, 0.f, 0.f, 0.f);

    const int base = chunk * ROWS + wave * RPW;  // 32 consecutive rows
    const float* __restrict__ rptr = rb + (size_t)base * C_ + lane;
    const float* __restrict__ vptr = vp + (size_t)base * D_ + d4;

    // ---- prologue: r for groups 0,1 first (ballot waits only on these),
    // then the first 8 v rows into the ring
    float rv0 = rptr[0];
    float rv1 = rptr[64];                        // group 1 (rows 4..7)
    float4 ring[8];
#pragma unroll
    for (int s = 0; s < 8; ++s)
        ring[s] = *(const float4*)(vptr + (size_t)s * D_);

#define ACCROW(VV, MASK)                                       \
    {                                                          \
        const unsigned _m = (MASK);                            \
        _Pragma("unroll")                                      \
        for (int c = 0; c < 16; ++c) {                         \
            const float m = (_m & (1u << c)) ? 1.0f : 0.0f;    \
            acc[c].x += (VV).x * m;                            \
            acc[c].y += (VV).y * m;                            \
            acc[c].z += (VV).z * m;                            \
            acc[c].w += (VV).w * m;                            \
        }                                                      \
        if (__builtin_expect(_m == 0u, 0)) {                   \
            acc[16].x += (VV).x; acc[16].y += (VV).y;          \
            acc[16].z += (VV).z; acc[16].w += (VV).w;          \
        }                                                      \
    }

#pragma unroll
    for (int g = 0; g < NGRP; ++g) {
        // consume this group's r (loaded 2 groups ago), reissue its slot
        const float rvc = (g & 1) ? rv1 : rv0;
        const unsigned long long bal = __ballot(rvc >= 0.5f);
        if (g + 2 < NGRP) {
            const float rnew = rptr[(size_t)(g + 2) * 64];
            if (g & 1) rv1 = rnew; else rv0 = rnew;
        }
#pragma unroll
        for (int rr = 0; rr < 4; ++rr) {
            const int row  = 4 * g + rr;
            const int slot = row & 7;
            const float4 vv = ring[slot];        // consume (vmcnt wait here)
            if (row + 8 < RPW)                   // reissue slot for row+8
                ring[slot] = *(const float4*)(vptr + (size_t)(row + 8) * D_);
            const unsigned mm = (unsigned)(bal >> (16 * rr)) & 0xFFFFu;
            ACCROW(vv, mm);
        }
    }

    // ---- cross-wave reduction in LDS (wave0 stores, waves 1..3 accumulate)
    __shared__ float4 lds4[17 * 64];    // 17 KiB
    if (wave == 0) {
#pragma unroll
        for (int c = 0; c < 17; ++c) lds4[c * 64 + lane] = acc[c];
    }
    __syncthreads();
    for (int w = 1; w < 4; ++w) {
        if (wave == w) {
#pragma unroll
            for (int c = 0; c < 17; ++c) {
                float4 t = lds4[c * 64 + lane];
                t.x += acc[c].x; t.y += acc[c].y;
                t.z += acc[c].z; t.w += acc[c].w;
                lds4[c * 64 + lane] = t;
            }
        }
        __syncthreads();
    }

    // ---- coalesced float4 partial store: ws[blk][17][256] (1088 float4)
    float4* __restrict__ wsb = (float4*)(ws + (size_t)blockIdx.x * 17 * D_);
#pragma unroll
    for (int i = 0; i < 4; ++i)
        wsb[i * 256 + tid] = lds4[i * 256 + tid];
    if (tid < 64)
        wsb[1024 + tid] = lds4[1024 + tid];
}

// ---------------- Stage 2: reduce 32 chunk-partials per output float4 ------
// One thread = one float4 of out (34816 total -> 136 blocks). idx
// enumerates (b, j, q) contiguously -> ws reads (per k) and the out
// write are perfectly coalesced. unroll 8 keeps 8 dwordx4 in flight.
__global__ __launch_bounds__(256, 8)
void tf_stage2(const float4* __restrict__ ws4, float4* __restrict__ out4) {
    const int idx = blockIdx.x * 256 + threadIdx.x;   // 0 .. 34815
    const int b   = idx / 1088;                       // 17 * 64 float4 per b
    const int rem = idx - b * 1088;

    const float4* __restrict__ p = ws4 + (size_t)b * (NSPLIT * 1088) + rem;
    float sx = 0.f, sy = 0.f, sz = 0.f, sw = 0.f;
#pragma unroll 8
    for (int k = 0; k < NSPLIT; ++k) {
        const float4 t = p[(size_t)k * 1088];
        sx += t.x; sy += t.y; sz += t.z; sw += t.w;
    }
    const float sc = 1.0f / (float)N_;
    out4[idx] = make_float4(sx * sc, sy * sc, sz * sc, sw * sc);
}

extern "C" void kernel_launch(void* const* d_in, const int* in_sizes, int n_in,
                              void* d_out, int out_size, void* d_ws, size_t ws_size,
                              hipStream_t stream) {
    const float* r = (const float*)d_in[0];   // (B,N,C) fp32
    const float* v = (const float*)d_in[1];   // (B,N,D) fp32
    float* out = (float*)d_out;               // (B,C+1,D) fp32
    float* ws  = (float*)d_ws;                // 17.8 MB used

    tf_stage1<<<dim3(B_ * NSPLIT), 256, 0, stream>>>(r, v, ws);
    // B*17*D/4 float4 outputs / 256 threads = 136 blocks
    tf_stage2<<<dim3((B_ * 17 * D_ / 4) / 256), 256, 0, stream>>>(
        (const float4*)ws, (float4*)out);
    // stage2 writes every out element -> no memset of d_out needed
}

// Round 4
// 200.864 us; speedup vs baseline: 1.1218x; 1.1218x over previous
//
#include <hip/hip_runtime.h>

#define B_ 32
#define N_ 4096
#define C_ 16
#define D_ 256
#define NSPLIT 32
#define ROWS (N_ / NSPLIT)   // 128 rows per block
#define RPW  (ROWS / 4)      // 32 rows per wave
#define NGRP (RPW / 4)       // 8 groups of 4 rows per wave

// ---------------- Stage 1: deep-ring partial sums -> ws (no atomics) -------
// VERBATIM the measured-best R0 kernel (200.7us total). Notes from this
// session's failed variants -- do not re-try:
//  * NSPLIT=16 (2 blocks/CU): +5us -- latency hiding loss > ws saving (R1)
//  * atomicAdd epilogue into out: +3us -- memory-side atomic throughput (R2)
//  * branch-skip of the acc[16] special row (__builtin_expect): VGPR
//    allocation collapses to 64 -> 73 MB scratch spills, stage1 88us (R3).
//    The branchless m in {0,1} multiply form is load-bearing for regalloc.
// One wave = one full row of D (64 lanes x float4). Ring of 8 rows in
// flight: consume row R, immediately reissue its slot for row R+8 ->
// ~8.25 KB outstanding per wave, 16 waves/CU co-resident (1024 blocks =
// 4 blocks/CU, single dispatch round). Masks: one 64-lane r-load covers a
// 4-row group; ballot -> wave-uniform 16-bit masks in SGPRs; accumulation
// acc[c] += v * m with m in {0,1} (scalar select feeding FMA, no
// divergence). Special (all-below) row -> 17th register accumulator.
__global__ __launch_bounds__(256, 4)
void tf_stage1(const float* __restrict__ r,
               const float* __restrict__ v,
               float* __restrict__ ws) {
    const int b     = blockIdx.x >> 5;           // / NSPLIT
    const int chunk = blockIdx.x & (NSPLIT - 1);
    const int tid   = threadIdx.x;
    const int wave  = tid >> 6;
    const int lane  = tid & 63;
    const int d4    = lane << 2;

    const float* __restrict__ rb = r + (size_t)b * N_ * C_;
    const float* __restrict__ vp = v + (size_t)b * N_ * D_;

    float4 acc[17];                              // [16] = special (all-below)
#pragma unroll
    for (int c = 0; c < 17; ++c) acc[c] = make_float4(0.f, 0.f, 0.f, 0.f);

    const int base = chunk * ROWS + wave * RPW;  // 32 consecutive rows
    const float* __restrict__ rptr = rb + (size_t)base * C_ + lane;
    const float* __restrict__ vptr = vp + (size_t)base * D_ + d4;

    // ---- prologue: r for groups 0,1 first (ballot waits only on these),
    // then the first 8 v rows into the ring
    float rv0 = rptr[0];
    float rv1 = rptr[64];                        // group 1 (rows 4..7)
    float4 ring[8];
#pragma unroll
    for (int s = 0; s < 8; ++s)
        ring[s] = *(const float4*)(vptr + (size_t)s * D_);

#define ACCROW(VV, MASK)                                       \
    {                                                          \
        const unsigned _m = (MASK);                            \
        _Pragma("unroll")                                      \
        for (int c = 0; c < 16; ++c) {                         \
            const float m = (_m & (1u << c)) ? 1.0f : 0.0f;    \
            acc[c].x += (VV).x * m;                            \
            acc[c].y += (VV).y * m;                            \
            acc[c].z += (VV).z * m;                            \
            acc[c].w += (VV).w * m;                            \
        }                                                      \
        const float ms = (_m == 0u) ? 1.0f : 0.0f;             \
        acc[16].x += (VV).x * ms; acc[16].y += (VV).y * ms;    \
        acc[16].z += (VV).z * ms; acc[16].w += (VV).w * ms;    \
    }

#pragma unroll
    for (int g = 0; g < NGRP; ++g) {
        // consume this group's r (loaded 2 groups ago), reissue its slot
        const float rvc = (g & 1) ? rv1 : rv0;
        const unsigned long long bal = __ballot(rvc >= 0.5f);
        if (g + 2 < NGRP) {
            const float rnew = rptr[(size_t)(g + 2) * 64];
            if (g & 1) rv1 = rnew; else rv0 = rnew;
        }
#pragma unroll
        for (int rr = 0; rr < 4; ++rr) {
            const int row  = 4 * g + rr;
            const int slot = row & 7;
            const float4 vv = ring[slot];        // consume (vmcnt wait here)
            if (row + 8 < RPW)                   // reissue slot for row+8
                ring[slot] = *(const float4*)(vptr + (size_t)(row + 8) * D_);
            const unsigned mm = (unsigned)(bal >> (16 * rr)) & 0xFFFFu;
            ACCROW(vv, mm);
        }
    }

    // ---- cross-wave reduction in LDS (wave0 stores, waves 1..3 accumulate)
    __shared__ float4 lds4[17 * 64];    // 17 KiB
    if (wave == 0) {
#pragma unroll
        for (int c = 0; c < 17; ++c) lds4[c * 64 + lane] = acc[c];
    }
    __syncthreads();
    for (int w = 1; w < 4; ++w) {
        if (wave == w) {
#pragma unroll
            for (int c = 0; c < 17; ++c) {
                float4 t = lds4[c * 64 + lane];
                t.x += acc[c].x; t.y += acc[c].y;
                t.z += acc[c].z; t.w += acc[c].w;
                lds4[c * 64 + lane] = t;
            }
        }
        __syncthreads();
    }

    // ---- coalesced partial store: ws[blk][17][256]
    float* __restrict__ wsb = ws + (size_t)blockIdx.x * 17 * D_;
    const float* lf = (const float*)lds4;
#pragma unroll
    for (int c = 0; c < 17; ++c) {
        wsb[c * D_ + tid] = lf[c * 256 + tid];
    }
}

// ---------------- Stage 2: reduce 32 chunk-partials per output float4 ------
// One thread = one float4 of out (34816 total -> 136 blocks). idx
// enumerates (b, j, q) contiguously -> ws reads (per k) and the out
// write are perfectly coalesced. unroll 8 keeps 8 dwordx4 in flight.
__global__ __launch_bounds__(256, 8)
void tf_stage2(const float4* __restrict__ ws4, float4* __restrict__ out4) {
    const int idx = blockIdx.x * 256 + threadIdx.x;   // 0 .. 34815
    const int b   = idx / 1088;                       // 17 * 64 float4 per b
    const int rem = idx - b * 1088;

    const float4* __restrict__ p = ws4 + (size_t)b * (NSPLIT * 1088) + rem;
    float sx = 0.f, sy = 0.f, sz = 0.f, sw = 0.f;
#pragma unroll 8
    for (int k = 0; k < NSPLIT; ++k) {
        const float4 t = p[(size_t)k * 1088];
        sx += t.x; sy += t.y; sz += t.z; sw += t.w;
    }
    const float sc = 1.0f / (float)N_;
    out4[idx] = make_float4(sx * sc, sy * sc, sz * sc, sw * sc);
}

extern "C" void kernel_launch(void* const* d_in, const int* in_sizes, int n_in,
                              void* d_out, int out_size, void* d_ws, size_t ws_size,
                              hipStream_t stream) {
    const float* r = (const float*)d_in[0];   // (B,N,C) fp32
    const float* v = (const float*)d_in[1];   // (B,N,D) fp32
    float* out = (float*)d_out;               // (B,C+1,D) fp32
    float* ws  = (float*)d_ws;                // 17.8 MB used

    tf_stage1<<<dim3(B_ * NSPLIT), 256, 0, stream>>>(r, v, ws);
    // B*17*D/4 float4 outputs / 256 threads = 136 blocks
    tf_stage2<<<dim3((B_ * 17 * D_ / 4) / 256), 256, 0, stream>>>(
        (const float4*)ws, (float4*)out);
    // stage2 writes every out element -> no memset of d_out needed
}